// Round 2
// baseline (959.668 us; speedup 1.0000x reference)
//
#include <hip/hip_runtime.h>
#include <math.h>

typedef __bf16 bf16x8 __attribute__((ext_vector_type(8)));
typedef __bf16 bf16x4 __attribute__((ext_vector_type(4)));
typedef float  f32x4  __attribute__((ext_vector_type(4)));

#define NTOK 4096
#define CDIM 1024
#define EEXP 8
#define IDIM 2048

__device__ __forceinline__ void async_copy16(const __bf16* g, __bf16* l) {
  __builtin_amdgcn_global_load_lds((const __attribute__((address_space(1))) void*)g,
                                   (__attribute__((address_space(3))) void*)l,
                                   16, 0, 0);
}

// ---------------- sim column inverse norms (1 block) ----------------
__global__ void simnorm_kernel(const float* __restrict__ sim, float* __restrict__ inv_norm) {
  const int tid = threadIdx.x;   // 256 threads: 8 groups of 32, group e
  const int e = tid >> 5;
  const int c0 = tid & 31;
  float ss = 0.f;
  for (int c = c0; c < CDIM; c += 32) {
    float v = sim[c * EEXP + e];
    ss = fmaf(v, v, ss);
  }
  #pragma unroll
  for (int off = 16; off > 0; off >>= 1) ss += __shfl_down(ss, off, 32);
  if (c0 == 0) inv_norm[e] = 1.f / fmaxf(sqrtf(ss), 1e-12f);
}

// ---------------- h fp32 -> bf16 ----------------
__global__ __launch_bounds__(256) void cvt_h_bf16(const float* __restrict__ in,
                                                  __bf16* __restrict__ out) {
  int i = blockIdx.x * 256 + threadIdx.x;   // one float4 per thread
  float4 v = ((const float4*)in)[i];
  bf16x4 o = {(__bf16)v.x, (__bf16)v.y, (__bf16)v.z, (__bf16)v.w};
  ((bf16x4*)out)[i] = o;
}

// ---------------- gating: one block per token (all fp32) ----------------
__global__ __launch_bounds__(256) void gating_kernel(
    const float* __restrict__ h, const float* __restrict__ sim,
    const float* __restrict__ gates, const float* __restrict__ temp,
    const float* __restrict__ emask, const int* __restrict__ minexp,
    const float* __restrict__ inv_simnorm,
    float* __restrict__ out_logits, float* __restrict__ out_act,
    float* __restrict__ s_scale)
{
  const int t = blockIdx.x, tid = threadIdx.x;
  float4 hv4 = ((const float4*)(h + (size_t)t * CDIM))[tid];
  float hv[4] = {hv4.x, hv4.y, hv4.z, hv4.w};
  float d[EEXP];
  #pragma unroll
  for (int e = 0; e < EEXP; ++e) d[e] = 0.f;
  float ss = 0.f;
  #pragma unroll
  for (int j = 0; j < 4; ++j) {
    ss = fmaf(hv[j], hv[j], ss);
    const float* sr = sim + (size_t)(tid * 4 + j) * EEXP;  // one sim row = 8 f32
    float4 s0 = ((const float4*)sr)[0];
    float4 s1 = ((const float4*)sr)[1];
    float sv[8] = {s0.x, s0.y, s0.z, s0.w, s1.x, s1.y, s1.z, s1.w};
    #pragma unroll
    for (int e = 0; e < EEXP; ++e) d[e] = fmaf(hv[j], sv[e], d[e]);
  }
  #pragma unroll
  for (int off = 32; off > 0; off >>= 1) {
    ss += __shfl_down(ss, off);
    #pragma unroll
    for (int e = 0; e < EEXP; ++e) d[e] += __shfl_down(d[e], off);
  }
  __shared__ float red[4][12];
  const int wv = tid >> 6;
  if ((tid & 63) == 0) {
    red[wv][0] = ss;
    #pragma unroll
    for (int e = 0; e < EEXP; ++e) red[wv][1 + e] = d[e];
  }
  __syncthreads();
  if (tid == 0) {
    float sst = red[0][0] + red[1][0] + red[2][0] + red[3][0];
    float inv_h = 1.f / fmaxf(sqrtf(sst), 1e-12f);
    float ls = 1.f / (1.f + expf(-temp[0]));
    float logit[EEXP], act[EEXP];
    float cnt = 0.f;
    #pragma unroll
    for (int e = 0; e < EEXP; ++e) {
      float dot = red[0][1 + e] + red[1][1 + e] + red[2][1 + e] + red[3][1 + e];
      logit[e] = dot * inv_h * inv_simnorm[e] * emask[e];
      float g = logit[e] - gates[e] * ls;   // relu(x)>0 <=> x>0
      act[e] = (g > 0.f) ? 1.f : 0.f;
      cnt += act[e];
    }
    if (cnt == 0.f) {  // fallback: top-min_experts by logits (ties -> lowest index)
      int k = minexp[0];
      if (k > EEXP) k = EEXP;
      bool used[EEXP];
      #pragma unroll
      for (int e = 0; e < EEXP; ++e) used[e] = false;
      for (int j = 0; j < k; ++j) {
        int best = -1; float bv = 0.f;
        for (int e = 0; e < EEXP; ++e)
          if (!used[e] && (best < 0 || logit[e] > bv)) { best = e; bv = logit[e]; }
        if (best >= 0) { used[best] = true; act[best] = 1.f; cnt += 1.f; }
      }
    }
    float num = fmaxf(cnt, 1.f);
    #pragma unroll
    for (int e = 0; e < EEXP; ++e) {
      out_logits[(size_t)t * EEXP + e] = logit[e];
      out_act[(size_t)t * EEXP + e]   = act[e];
      s_scale[(size_t)t * EEXP + e]   = act[e] / num;
    }
  }
}

// ---------------- fp32 64x64 tiled transpose+convert: out_bf16[c][r] = in_f32[r][c] ----------------
__global__ __launch_bounds__(256) void transpose_f32_bf16(
    const float* __restrict__ in, __bf16* __restrict__ out, int R, int Cc)
{
  __shared__ __align__(16) __bf16 tile[64][72];  // 72: pad keeps 16B alignment per row
  const int tid = threadIdx.x;
  const int c0 = blockIdx.x * 64, r0 = blockIdx.y * 64;
  #pragma unroll
  for (int p = 0; p < 2; ++p) {
    int lin = p * 256 + tid;        // 512 chunks of 8 elements
    int r = lin >> 3, c8 = (lin & 7) * 8;
    const float* src = in + (size_t)(r0 + r) * Cc + c0 + c8;
    float4 v0 = ((const float4*)src)[0];
    float4 v1 = ((const float4*)src)[1];
    bf16x8 v = {(__bf16)v0.x, (__bf16)v0.y, (__bf16)v0.z, (__bf16)v0.w,
                (__bf16)v1.x, (__bf16)v1.y, (__bf16)v1.z, (__bf16)v1.w};
    *(bf16x8*)&tile[r][c8] = v;
  }
  __syncthreads();
  #pragma unroll
  for (int p = 0; p < 2; ++p) {
    int lin = p * 256 + tid;
    int oc = lin >> 3, j8 = (lin & 7) * 8;
    bf16x8 o;
    #pragma unroll
    for (int jj = 0; jj < 8; ++jj) o[jj] = tile[j8 + jj][oc];
    *(bf16x8*)(out + (size_t)(c0 + oc) * R + r0 + j8) = o;
  }
}

// ---------------- m97-style bf16 GEMM, C[m][n] = sum_k A[m][k]*B[n][k] ----------------
// MODE 0: epilogue gelu(acc)*s[row*8] -> bf16 Cout (inter)
// MODE 1: epilogue fp32 (accumulate ? += : =) into Cout
template <int MODE>
__global__ __launch_bounds__(256, 2) void gemm_bt(
    const __bf16* __restrict__ A, const __bf16* __restrict__ B,
    int M, int N, int K, void* __restrict__ Cout,
    const float* __restrict__ s_e, int accumulate)
{
  __shared__ __align__(16) __bf16 As[128 * 32];
  __shared__ __align__(16) __bf16 Bs[128 * 32];
  const int tid = threadIdx.x;
  const int wave = tid >> 6, lane = tid & 63;
  const int m0 = blockIdx.y * 128, n0 = blockIdx.x * 128;
  const int wm = (wave >> 1) * 64, wn = (wave & 1) * 64;
  const int quad = lane >> 4, lrow = lane & 15;

  const int srow = lane >> 2;        // row within 16-row staging chunk
  const int skol = (lane & 3) * 8;   // k element offset (16B granules)

  const __bf16* Ab = A + (size_t)(m0 + wave * 32 + srow) * K + skol;
  const __bf16* Bb = B + (size_t)(n0 + wave * 32 + srow) * K + skol;
  __bf16* lA = As + wave * 1024;     // wave-uniform base; HW adds lane*16B
  __bf16* lB = Bs + wave * 1024;

  f32x4 acc[4][4] = {};

  for (int k0 = 0; k0 < K; k0 += 32) {
    async_copy16(Ab + k0, lA);
    async_copy16(Ab + (size_t)16 * K + k0, lA + 512);
    async_copy16(Bb + k0, lB);
    async_copy16(Bb + (size_t)16 * K + k0, lB + 512);
    __syncthreads();
    bf16x8 af[4], bfr[4];
    #pragma unroll
    for (int mi = 0; mi < 4; ++mi)
      af[mi] = *(const bf16x8*)(As + (wm + mi * 16 + lrow) * 32 + quad * 8);
    #pragma unroll
    for (int ni = 0; ni < 4; ++ni)
      bfr[ni] = *(const bf16x8*)(Bs + (wn + ni * 16 + lrow) * 32 + quad * 8);
    #pragma unroll
    for (int mi = 0; mi < 4; ++mi)
      #pragma unroll
      for (int ni = 0; ni < 4; ++ni)
        acc[mi][ni] = __builtin_amdgcn_mfma_f32_16x16x32_bf16(af[mi], bfr[ni], acc[mi][ni], 0, 0, 0);
    __syncthreads();
  }

  if (MODE == 0) {
    __bf16* O = (__bf16*)Cout;
    #pragma unroll
    for (int mi = 0; mi < 4; ++mi) {
      #pragma unroll
      for (int r = 0; r < 4; ++r) {
        const int row = m0 + wm + mi * 16 + quad * 4 + r;
        const float sv = s_e[(size_t)row * EEXP];
        #pragma unroll
        for (int ni = 0; ni < 4; ++ni) {
          const int col = n0 + wn + ni * 16 + lrow;
          float v = acc[mi][ni][r];
          v = 0.5f * v * (1.f + erff(v * 0.70710678118654752440f));  // exact gelu
          O[(size_t)row * N + col] = (__bf16)(v * sv);
        }
      }
    }
  } else {
    float* O = (float*)Cout;
    #pragma unroll
    for (int mi = 0; mi < 4; ++mi) {
      #pragma unroll
      for (int r = 0; r < 4; ++r) {
        const int row = m0 + wm + mi * 16 + quad * 4 + r;
        #pragma unroll
        for (int ni = 0; ni < 4; ++ni) {
          const int col = n0 + wn + ni * 16 + lrow;
          const size_t idx = (size_t)row * N + col;
          float v = acc[mi][ni][r];
          if (accumulate) v += O[idx];
          O[idx] = v;
        }
      }
    }
  }
}

extern "C" void kernel_launch(void* const* d_in, const int* in_sizes, int n_in,
                              void* d_out, int out_size, void* d_ws, size_t ws_size,
                              hipStream_t stream) {
  (void)in_sizes; (void)n_in; (void)out_size; (void)ws_size;
  const float* h     = (const float*)d_in[0];
  const float* sim   = (const float*)d_in[1];
  const float* gates = (const float*)d_in[2];
  const float* temp  = (const float*)d_in[3];
  const float* emask = (const float*)d_in[4];
  const float* w1    = (const float*)d_in[5];
  const float* w2    = (const float*)d_in[6];
  const int*   minexp = (const int*)d_in[7];

  float* out_final  = (float*)d_out;                        // [4096][1024]
  float* out_logits = out_final + (size_t)NTOK * CDIM;      // [4096][8]
  float* out_act    = out_logits + (size_t)NTOK * EEXP;     // [4096][8]

  char* ws = (char*)d_ws;                                   // ~33.7 MB used
  float*  inv_simnorm = (float*)(ws + 0);                   // 8 f32
  float*  s_scale     = (float*)(ws + 256);                 // [4096][8] f32 (128KB)
  __bf16* w1T         = (__bf16*)(ws + 131328);             // [2048][1024] bf16 (4MB), per-expert reuse
  __bf16* w2T         = (__bf16*)(ws + 4325632);            // [1024][2048] bf16 (4MB)
  __bf16* hb          = (__bf16*)(ws + 8519936);            // [4096][1024] bf16 (8MB)
  __bf16* inter       = (__bf16*)(ws + 16908544);           // [4096][2048] bf16 (16MB)

  simnorm_kernel<<<1, 256, 0, stream>>>(sim, inv_simnorm);
  gating_kernel<<<NTOK, 256, 0, stream>>>(h, sim, gates, temp, emask, minexp,
                                          inv_simnorm, out_logits, out_act, s_scale);
  cvt_h_bf16<<<NTOK * CDIM / 4 / 256, 256, 0, stream>>>(h, hb);
  for (int e = 0; e < EEXP; ++e) {
    // w1[e]: [C][I] f32 -> w1T [I][C] bf16;  w2[e]: [I][C] f32 -> w2T [C][I] bf16
    transpose_f32_bf16<<<dim3(IDIM / 64, CDIM / 64), 256, 0, stream>>>(
        w1 + (size_t)e * CDIM * IDIM, w1T, CDIM, IDIM);
    transpose_f32_bf16<<<dim3(CDIM / 64, IDIM / 64), 256, 0, stream>>>(
        w2 + (size_t)e * CDIM * IDIM, w2T, IDIM, CDIM);
    // inter = gelu(hb @ w1[e]) * s[:,e]   (M=4096, N=2048, K=1024)
    gemm_bt<0><<<dim3(IDIM / 128, NTOK / 128), 256, 0, stream>>>(
        hb, w1T, NTOK, IDIM, CDIM, (void*)inter, s_scale + e, 0);
    // out_final (+)= inter @ w2[e]        (M=4096, N=1024, K=2048)
    gemm_bt<1><<<dim3(CDIM / 128, NTOK / 128), 256, 0, stream>>>(
        inter, w2T, NTOK, CDIM, IDIM, (void*)out_final, nullptr, e ? 1 : 0);
  }
}

// Round 3
// 617.925 us; speedup vs baseline: 1.5530x; 1.5530x over previous
//
#include <hip/hip_runtime.h>
#include <math.h>

typedef __bf16 bf16x8 __attribute__((ext_vector_type(8)));
typedef __bf16 bf16x4 __attribute__((ext_vector_type(4)));
typedef float  f32x4  __attribute__((ext_vector_type(4)));

#define NTOK 4096
#define CDIM 1024
#define EEXP 8
#define IDIM 2048

__device__ __forceinline__ void async_copy16(const __bf16* g, __bf16* l) {
  __builtin_amdgcn_global_load_lds((const __attribute__((address_space(1))) void*)g,
                                   (__attribute__((address_space(3))) void*)l,
                                   16, 0, 0);
}

// ---------------- sim column inverse norms (1 block) ----------------
__global__ void simnorm_kernel(const float* __restrict__ sim, float* __restrict__ inv_norm) {
  const int tid = threadIdx.x;   // 256 threads: 8 groups of 32, group e
  const int e = tid >> 5;
  const int c0 = tid & 31;
  float ss = 0.f;
  for (int c = c0; c < CDIM; c += 32) {
    float v = sim[c * EEXP + e];
    ss = fmaf(v, v, ss);
  }
  #pragma unroll
  for (int off = 16; off > 0; off >>= 1) ss += __shfl_down(ss, off, 32);
  if (c0 == 0) inv_norm[e] = 1.f / fmaxf(sqrtf(ss), 1e-12f);
}

// ---------------- h fp32 -> bf16 ----------------
__global__ __launch_bounds__(256) void cvt_h_bf16(const float* __restrict__ in,
                                                  __bf16* __restrict__ out) {
  int i = blockIdx.x * 256 + threadIdx.x;   // one float4 per thread
  float4 v = ((const float4*)in)[i];
  bf16x4 o = {(__bf16)v.x, (__bf16)v.y, (__bf16)v.z, (__bf16)v.w};
  ((bf16x4*)out)[i] = o;
}

// ---------------- gating: one block per token (all fp32) ----------------
__global__ __launch_bounds__(256) void gating_kernel(
    const float* __restrict__ h, const float* __restrict__ sim,
    const float* __restrict__ gates, const float* __restrict__ temp,
    const float* __restrict__ emask, const int* __restrict__ minexp,
    const float* __restrict__ inv_simnorm,
    float* __restrict__ out_logits, float* __restrict__ out_act,
    float* __restrict__ s_scale)
{
  const int t = blockIdx.x, tid = threadIdx.x;
  float4 hv4 = ((const float4*)(h + (size_t)t * CDIM))[tid];
  float hv[4] = {hv4.x, hv4.y, hv4.z, hv4.w};
  float d[EEXP];
  #pragma unroll
  for (int e = 0; e < EEXP; ++e) d[e] = 0.f;
  float ss = 0.f;
  #pragma unroll
  for (int j = 0; j < 4; ++j) {
    ss = fmaf(hv[j], hv[j], ss);
    const float* sr = sim + (size_t)(tid * 4 + j) * EEXP;  // one sim row = 8 f32
    float4 s0 = ((const float4*)sr)[0];
    float4 s1 = ((const float4*)sr)[1];
    float sv[8] = {s0.x, s0.y, s0.z, s0.w, s1.x, s1.y, s1.z, s1.w};
    #pragma unroll
    for (int e = 0; e < EEXP; ++e) d[e] = fmaf(hv[j], sv[e], d[e]);
  }
  #pragma unroll
  for (int off = 32; off > 0; off >>= 1) {
    ss += __shfl_down(ss, off);
    #pragma unroll
    for (int e = 0; e < EEXP; ++e) d[e] += __shfl_down(d[e], off);
  }
  __shared__ float red[4][12];
  const int wv = tid >> 6;
  if ((tid & 63) == 0) {
    red[wv][0] = ss;
    #pragma unroll
    for (int e = 0; e < EEXP; ++e) red[wv][1 + e] = d[e];
  }
  __syncthreads();
  if (tid == 0) {
    float sst = red[0][0] + red[1][0] + red[2][0] + red[3][0];
    float inv_h = 1.f / fmaxf(sqrtf(sst), 1e-12f);
    float ls = 1.f / (1.f + expf(-temp[0]));
    float logit[EEXP], act[EEXP];
    float cnt = 0.f;
    #pragma unroll
    for (int e = 0; e < EEXP; ++e) {
      float dot = red[0][1 + e] + red[1][1 + e] + red[2][1 + e] + red[3][1 + e];
      logit[e] = dot * inv_h * inv_simnorm[e] * emask[e];
      float g = logit[e] - gates[e] * ls;   // relu(x)>0 <=> x>0
      act[e] = (g > 0.f) ? 1.f : 0.f;
      cnt += act[e];
    }
    if (cnt == 0.f) {  // fallback: top-min_experts by logits (ties -> lowest index)
      int k = minexp[0];
      if (k > EEXP) k = EEXP;
      bool used[EEXP];
      #pragma unroll
      for (int e = 0; e < EEXP; ++e) used[e] = false;
      for (int j = 0; j < k; ++j) {
        int best = -1; float bv = 0.f;
        for (int e = 0; e < EEXP; ++e)
          if (!used[e] && (best < 0 || logit[e] > bv)) { best = e; bv = logit[e]; }
        if (best >= 0) { used[best] = true; act[best] = 1.f; cnt += 1.f; }
      }
    }
    float num = fmaxf(cnt, 1.f);
    #pragma unroll
    for (int e = 0; e < EEXP; ++e) {
      out_logits[(size_t)t * EEXP + e] = logit[e];
      out_act[(size_t)t * EEXP + e]   = act[e];
      s_scale[(size_t)t * EEXP + e]   = act[e] / num;
    }
  }
}

// ---------------- fp32 64x64 tiled transpose+convert: out_bf16[c][r] = in_f32[r][c] ----------------
// blockIdx.z = expert (strides in elements)
__global__ __launch_bounds__(256) void transpose_f32_bf16(
    const float* __restrict__ in0, __bf16* __restrict__ out0, int R, int Cc,
    long sIn, long sOut)
{
  const float* in = in0 + (size_t)blockIdx.z * sIn;
  __bf16* out = out0 + (size_t)blockIdx.z * sOut;
  __shared__ __align__(16) __bf16 tile[64][72];  // 72: pad keeps 16B alignment per row
  const int tid = threadIdx.x;
  const int c0 = blockIdx.x * 64, r0 = blockIdx.y * 64;
  #pragma unroll
  for (int p = 0; p < 2; ++p) {
    int lin = p * 256 + tid;        // 512 chunks of 8 elements
    int r = lin >> 3, c8 = (lin & 7) * 8;
    const float* src = in + (size_t)(r0 + r) * Cc + c0 + c8;
    float4 v0 = ((const float4*)src)[0];
    float4 v1 = ((const float4*)src)[1];
    bf16x8 v = {(__bf16)v0.x, (__bf16)v0.y, (__bf16)v0.z, (__bf16)v0.w,
                (__bf16)v1.x, (__bf16)v1.y, (__bf16)v1.z, (__bf16)v1.w};
    *(bf16x8*)&tile[r][c8] = v;
  }
  __syncthreads();
  #pragma unroll
  for (int p = 0; p < 2; ++p) {
    int lin = p * 256 + tid;
    int oc = lin >> 3, j8 = (lin & 7) * 8;
    bf16x8 o;
    #pragma unroll
    for (int jj = 0; jj < 8; ++jj) o[jj] = tile[j8 + jj][oc];
    *(bf16x8*)(out + (size_t)(c0 + oc) * R + r0 + j8) = o;
  }
}

// ---------------- m97-style bf16 GEMM, C[m][n] = sum_k A[m][k]*B[n][k] ----------------
// Batched over blockIdx.z with per-expert element strides sAe/sBe/sCe.
// MODE 0: epilogue gelu(acc)*s_scale[ez + row*8] -> bf16 Cout        (gemm1)
// MODE 1: epilogue fp32 (accumulate ? += : =) into Cout              (fallback gemm2)
// MODE 2: K-loop over EPERZ experts, epilogue fp32 atomicAdd to Cout (batched gemm2)
template <int MODE, int EPERZ>
__global__ __launch_bounds__(256, 2) void gemm_moe(
    const __bf16* __restrict__ A0, const __bf16* __restrict__ B0,
    int M, int N, int K, long sAe, long sBe, long sCe,
    void* __restrict__ Cout, const float* __restrict__ s_scale, int accumulate)
{
  __shared__ __align__(16) __bf16 As[128 * 32];
  __shared__ __align__(16) __bf16 Bs[128 * 32];
  const int tid = threadIdx.x;
  const int wave = tid >> 6, lane = tid & 63;
  const int m0 = blockIdx.y * 128, n0 = blockIdx.x * 128;
  const int ez = blockIdx.z * EPERZ;
  const int wm = (wave >> 1) * 64, wn = (wave & 1) * 64;
  const int quad = lane >> 4, lrow = lane & 15;

  const int srow = lane >> 2;        // row within 16-row staging chunk
  const int skol = (lane & 3) * 8;   // k element offset (16B granules)

  __bf16* lA = As + wave * 1024;     // wave-uniform base; HW adds lane*16B
  __bf16* lB = Bs + wave * 1024;

  f32x4 acc[4][4] = {};

  for (int ee = 0; ee < EPERZ; ++ee) {
    const __bf16* Ab = A0 + (size_t)(ez + ee) * sAe
                     + (size_t)(m0 + wave * 32 + srow) * K + skol;
    const __bf16* Bb = B0 + (size_t)(ez + ee) * sBe
                     + (size_t)(n0 + wave * 32 + srow) * K + skol;
    for (int k0 = 0; k0 < K; k0 += 32) {
      async_copy16(Ab + k0, lA);
      async_copy16(Ab + (size_t)16 * K + k0, lA + 512);
      async_copy16(Bb + k0, lB);
      async_copy16(Bb + (size_t)16 * K + k0, lB + 512);
      __syncthreads();
      bf16x8 af[4], bfr[4];
      #pragma unroll
      for (int mi = 0; mi < 4; ++mi)
        af[mi] = *(const bf16x8*)(As + (wm + mi * 16 + lrow) * 32 + quad * 8);
      #pragma unroll
      for (int ni = 0; ni < 4; ++ni)
        bfr[ni] = *(const bf16x8*)(Bs + (wn + ni * 16 + lrow) * 32 + quad * 8);
      #pragma unroll
      for (int mi = 0; mi < 4; ++mi)
        #pragma unroll
        for (int ni = 0; ni < 4; ++ni)
          acc[mi][ni] = __builtin_amdgcn_mfma_f32_16x16x32_bf16(af[mi], bfr[ni], acc[mi][ni], 0, 0, 0);
      __syncthreads();
    }
  }

  if (MODE == 0) {
    __bf16* O = (__bf16*)Cout + (size_t)ez * sCe;
    const float* s_e = s_scale + ez;
    #pragma unroll
    for (int mi = 0; mi < 4; ++mi) {
      #pragma unroll
      for (int r = 0; r < 4; ++r) {
        const int row = m0 + wm + mi * 16 + quad * 4 + r;
        const float sv = s_e[(size_t)row * EEXP];
        #pragma unroll
        for (int ni = 0; ni < 4; ++ni) {
          const int col = n0 + wn + ni * 16 + lrow;
          float v = acc[mi][ni][r];
          v = 0.5f * v * (1.f + erff(v * 0.70710678118654752440f));  // exact gelu
          O[(size_t)row * N + col] = (__bf16)(v * sv);
        }
      }
    }
  } else if (MODE == 1) {
    float* O = (float*)Cout;
    #pragma unroll
    for (int mi = 0; mi < 4; ++mi) {
      #pragma unroll
      for (int r = 0; r < 4; ++r) {
        const int row = m0 + wm + mi * 16 + quad * 4 + r;
        #pragma unroll
        for (int ni = 0; ni < 4; ++ni) {
          const int col = n0 + wn + ni * 16 + lrow;
          const size_t idx = (size_t)row * N + col;
          float v = acc[mi][ni][r];
          if (accumulate) v += O[idx];
          O[idx] = v;
        }
      }
    }
  } else {
    float* O = (float*)Cout;
    #pragma unroll
    for (int mi = 0; mi < 4; ++mi) {
      #pragma unroll
      for (int r = 0; r < 4; ++r) {
        const int row = m0 + wm + mi * 16 + quad * 4 + r;
        #pragma unroll
        for (int ni = 0; ni < 4; ++ni) {
          const int col = n0 + wn + ni * 16 + lrow;
          atomicAdd(&O[(size_t)row * N + col], acc[mi][ni][r]);
        }
      }
    }
  }
}

extern "C" void kernel_launch(void* const* d_in, const int* in_sizes, int n_in,
                              void* d_out, int out_size, void* d_ws, size_t ws_size,
                              hipStream_t stream) {
  (void)in_sizes; (void)n_in; (void)out_size;
  const float* h     = (const float*)d_in[0];
  const float* sim   = (const float*)d_in[1];
  const float* gates = (const float*)d_in[2];
  const float* temp  = (const float*)d_in[3];
  const float* emask = (const float*)d_in[4];
  const float* w1    = (const float*)d_in[5];
  const float* w2    = (const float*)d_in[6];
  const int*   minexp = (const int*)d_in[7];

  float* out_final  = (float*)d_out;                        // [4096][1024]
  float* out_logits = out_final + (size_t)NTOK * CDIM;      // [4096][8]
  float* out_act    = out_logits + (size_t)NTOK * EEXP;     // [4096][8]

  char* ws = (char*)d_ws;
  float*  inv_simnorm = (float*)(ws + 0);                   // 8 f32
  float*  s_scale     = (float*)(ws + 256);                 // [4096][8] f32 (128KB)

  const long sW = (long)CDIM * IDIM;          // per-expert weight elements (2M)
  const long sI = (long)NTOK * IDIM;          // per-expert inter elements (8M)

  if (ws_size >= 209846528ULL) {
    // ---------- batched path (~200.2 MB ws) ----------
    __bf16* hb        = (__bf16*)(ws + 131328);             // [4096][1024] bf16 (8MB)
    __bf16* w1T_all   = (__bf16*)(ws + 8519936);            // [E][2048][1024] bf16 (32MB)
    __bf16* w2T_all   = (__bf16*)(ws + 42074368);           // [E][1024][2048] bf16 (32MB)
    __bf16* inter_all = (__bf16*)(ws + 75628800);           // [E][4096][2048] bf16 (128MB)

    simnorm_kernel<<<1, 256, 0, stream>>>(sim, inv_simnorm);
    gating_kernel<<<NTOK, 256, 0, stream>>>(h, sim, gates, temp, emask, minexp,
                                            inv_simnorm, out_logits, out_act, s_scale);
    cvt_h_bf16<<<NTOK * CDIM / 4 / 256, 256, 0, stream>>>(h, hb);
    // w1[e]: [C][I] f32 -> w1T [I][C] bf16;  w2[e]: [I][C] f32 -> w2T [C][I] bf16
    transpose_f32_bf16<<<dim3(IDIM / 64, CDIM / 64, EEXP), 256, 0, stream>>>(
        w1, w1T_all, CDIM, IDIM, sW, sW);
    transpose_f32_bf16<<<dim3(CDIM / 64, IDIM / 64, EEXP), 256, 0, stream>>>(
        w2, w2T_all, IDIM, CDIM, sW, sW);
    hipMemsetAsync(out_final, 0, (size_t)NTOK * CDIM * sizeof(float), stream);
    // gemm1 (all experts): inter_all[e] = gelu(hb @ w1[e]) * s[:,e]
    gemm_moe<0, 1><<<dim3(IDIM / 128, NTOK / 128, EEXP), 256, 0, stream>>>(
        hb, w1T_all, NTOK, IDIM, CDIM, 0, sW, sI, (void*)inter_all, s_scale, 0);
    // gemm2 (2 experts per z-slice, atomic fp32 accumulate into out_final)
    gemm_moe<2, 2><<<dim3(CDIM / 128, NTOK / 128, EEXP / 2), 256, 0, stream>>>(
        inter_all, w2T_all, NTOK, CDIM, IDIM, sI, sW, 0, (void*)out_final, nullptr, 0);
  } else {
    // ---------- fallback: round-2 per-expert path (~33.7 MB ws) ----------
    __bf16* w1T   = (__bf16*)(ws + 131328);                 // [2048][1024] bf16 (4MB)
    __bf16* w2T   = (__bf16*)(ws + 4325632);                // [1024][2048] bf16 (4MB)
    __bf16* hb    = (__bf16*)(ws + 8519936);                // [4096][1024] bf16 (8MB)
    __bf16* inter = (__bf16*)(ws + 16908544);               // [4096][2048] bf16 (16MB)

    simnorm_kernel<<<1, 256, 0, stream>>>(sim, inv_simnorm);
    gating_kernel<<<NTOK, 256, 0, stream>>>(h, sim, gates, temp, emask, minexp,
                                            inv_simnorm, out_logits, out_act, s_scale);
    cvt_h_bf16<<<NTOK * CDIM / 4 / 256, 256, 0, stream>>>(h, hb);
    for (int e = 0; e < EEXP; ++e) {
      transpose_f32_bf16<<<dim3(IDIM / 64, CDIM / 64, 1), 256, 0, stream>>>(
          w1 + (size_t)e * sW, w1T, CDIM, IDIM, 0, 0);
      transpose_f32_bf16<<<dim3(CDIM / 64, IDIM / 64, 1), 256, 0, stream>>>(
          w2 + (size_t)e * sW, w2T, IDIM, CDIM, 0, 0);
      gemm_moe<0, 1><<<dim3(IDIM / 128, NTOK / 128, 1), 256, 0, stream>>>(
          hb, w1T, NTOK, IDIM, CDIM, 0, 0, 0, (void*)inter, s_scale + e, 0);
      gemm_moe<1, 1><<<dim3(CDIM / 128, NTOK / 128, 1), 256, 0, stream>>>(
          inter, w2T, NTOK, CDIM, IDIM, 0, 0, 0, (void*)out_final, nullptr, e ? 1 : 0);
    }
  }
}